// Round 6
// baseline (173.137 us; speedup 1.0000x reference)
//
#include <hip/hip_runtime.h>

#define N_VARS 50000
#define N_TX   200000
#define DSZ    32

#define NWAVES 4000                    // single resident batch (16 waves/CU x 256 CU)
#define NPAIRS (N_TX / 2)              // 100000
#define PAIRS_PER_WAVE (NPAIRS / NWAVES)   // 25, exact

typedef float f32x4 __attribute__((ext_vector_type(4)));

// out = theta (residual initialization), one float4 per thread, single pass
__global__ void copy_theta_kernel(const float4* __restrict__ theta,
                                  float4* __restrict__ out, int n4) {
    int i = blockIdx.x * blockDim.x + threadIdx.x;
    if (i < n4) out[i] = theta[i];
}

// Pair-granularity grid-stride: wave w processes pairs {w, w+NWAVES, ...} so the
// 4000 resident waves collectively sweep one contiguous window of W forward.
// Lane l covers W flat float4 at lane*4 within each 1KiB quarter:
//   row i = it*8 + (l>>3), cols j0 = (l&7)*4.
// Reduction: value-splitting butterfly (7 shfl instead of 24) — after 3 steps
// lane l holds the full dot for edge (l&4? B:A), row (l&3)*8 + (l>>3).
__global__ __launch_bounds__(256)
void transform_scatter_kernel(const float* __restrict__ theta,
                              const float* __restrict__ W,
                              const float* __restrict__ bia,
                              const int* __restrict__ src,
                              const int* __restrict__ tgt,
                              float* __restrict__ out) {
    const int lane = threadIdx.x & 63;
    const int wave = (blockIdx.x * blockDim.x + threadIdx.x) >> 6;

    const int j0    = (lane & 7) << 2;        // this lane's 4-wide col slice
    const int g     = lane >> 3;              // row-group within the 8-row band
    const int myRow = (lane & 3) * 8 + g;     // row this lane finally owns
    const int hiB   = (lane >> 2) & 1;        // 1 -> this lane owns edge B

    for (int it = 0; it < PAIRS_PER_WAVE; ++it) {
        const int p = wave + it * NWAVES;
        const int e = 2 * p;

        const int2 sp = *reinterpret_cast<const int2*>(src + e);  // {sA, sB}
        const int2 tp = *reinterpret_cast<const int2*>(tgt + e);  // {tA, tB}

        const f32x4 xA = *reinterpret_cast<const f32x4*>(theta + (size_t)sp.x * DSZ + j0);
        const f32x4 xB = *reinterpret_cast<const f32x4*>(theta + (size_t)sp.y * DSZ + j0);

        const f32x4* WA = reinterpret_cast<const f32x4*>(W + (size_t)e * (DSZ * DSZ));
        const f32x4* WB = WA + 256;

        // 8 KiB in flight — plain loads (NT hint removed: A/B vs R4)
        const f32x4 a0 = WA[  0 + lane];
        const f32x4 a1 = WA[ 64 + lane];
        const f32x4 a2 = WA[128 + lane];
        const f32x4 a3 = WA[192 + lane];
        const f32x4 c0 = WB[  0 + lane];
        const f32x4 c1 = WB[ 64 + lane];
        const f32x4 c2 = WB[128 + lane];
        const f32x4 c3 = WB[192 + lane];

        // one bias element per lane (its own edge + row)
        const float biasv = bia[((size_t)e + hiB) * DSZ + myRow];

        float pA0 = a0.x * xA.x + a0.y * xA.y + a0.z * xA.z + a0.w * xA.w;
        float pA1 = a1.x * xA.x + a1.y * xA.y + a1.z * xA.z + a1.w * xA.w;
        float pA2 = a2.x * xA.x + a2.y * xA.y + a2.z * xA.z + a2.w * xA.w;
        float pA3 = a3.x * xA.x + a3.y * xA.y + a3.z * xA.z + a3.w * xA.w;
        float pB0 = c0.x * xB.x + c0.y * xB.y + c0.z * xB.z + c0.w * xB.w;
        float pB1 = c1.x * xB.x + c1.y * xB.y + c1.z * xB.z + c1.w * xB.w;
        float pB2 = c2.x * xB.x + c2.y * xB.y + c2.z * xB.z + c2.w * xB.w;
        float pB3 = c3.x * xB.x + c3.y * xB.y + c3.z * xB.z + c3.w * xB.w;

        // ---- value-splitting butterfly: 8 values over 8 lanes, 7 shfl ----
        const bool b0 = (lane & 1) != 0;
        const bool b1 = (lane & 2) != 0;
        const bool b2 = (lane & 4) != 0;

        // step 1 (xor 1): it-parity split; keep it = (l&1) within each family
        float vA01 = b0 ? pA1 : pA0, oA01 = b0 ? pA0 : pA1;
        float vA23 = b0 ? pA3 : pA2, oA23 = b0 ? pA2 : pA3;
        float vB01 = b0 ? pB1 : pB0, oB01 = b0 ? pB0 : pB1;
        float vB23 = b0 ? pB3 : pB2, oB23 = b0 ? pB2 : pB3;
        vA01 += __shfl_xor(oA01, 1);
        vA23 += __shfl_xor(oA23, 1);
        vB01 += __shfl_xor(oB01, 1);
        vB23 += __shfl_xor(oB23, 1);

        // step 2 (xor 2): it-high-bit split; lane now holds it = l&3
        float vA = b1 ? vA23 : vA01, oA = b1 ? vA01 : vA23;
        float vB = b1 ? vB23 : vB01, oB = b1 ? vB01 : vB23;
        vA += __shfl_xor(oA, 2);
        vB += __shfl_xor(oB, 2);

        // step 3 (xor 4): edge split; lane holds its final total
        float v = b2 ? vB : vA, o = b2 ? vA : vB;
        v += __shfl_xor(o, 4);

        const int te = b2 ? tp.y : tp.x;
        atomicAdd(out + (size_t)te * DSZ + myRow, -(v + biasv));
    }
}

extern "C" void kernel_launch(void* const* d_in, const int* in_sizes, int n_in,
                              void* d_out, int out_size, void* d_ws, size_t ws_size,
                              hipStream_t stream) {
    const float* theta = (const float*)d_in[0];
    const float* W     = (const float*)d_in[1];
    const float* b     = (const float*)d_in[2];
    const int*   src   = (const int*)d_in[3];
    const int*   tgt   = (const int*)d_in[4];
    float* out = (float*)d_out;

    // 1) out = theta (single pass)
    const int n4 = (N_VARS * DSZ) / 4;             // 400,000 float4s
    copy_theta_kernel<<<(n4 + 255) / 256, 256, 0, stream>>>(
        (const float4*)theta, (float4*)out, n4);

    // 2) scatter transforms: 4000 waves, pair grid-stride (global sliding window)
    transform_scatter_kernel<<<NWAVES / 4, 256, 0, stream>>>(theta, W, b, src, tgt, out);
}

// Round 7
// 156.076 us; speedup vs baseline: 1.1093x; 1.1093x over previous
//
#include <hip/hip_runtime.h>

#define N_VARS 50000
#define N_TX   200000
#define DSZ    32

#define NWAVES 4000                    // single resident batch (16 waves/CU x 256 CU)
#define NPAIRS (N_TX / 2)              // 100000
#define PAIRS_PER_WAVE (NPAIRS / NWAVES)   // 25, exact

typedef float f32x4 __attribute__((ext_vector_type(4)));

// out = theta (residual initialization), one float4 per thread, single pass
__global__ void copy_theta_kernel(const float4* __restrict__ theta,
                                  float4* __restrict__ out, int n4) {
    int i = blockIdx.x * blockDim.x + threadIdx.x;
    if (i < n4) out[i] = theta[i];
}

// Pair-granularity grid-stride: wave w processes pairs {w, w+NWAVES, ...} so the
// 4000 resident waves collectively sweep one contiguous window of W forward.
// Lane l covers W flat float4 at lane*4 within each 1KiB quarter:
//   row i = it*8 + (l>>3), cols j0 = (l&7)*4.
// W/bias loads are NONTEMPORAL (zero reuse; keeps L2 for theta gathers + out
// atomics — removing nt cost +18us in R5's A/B).
// Reduction: value-splitting butterfly (7 shfl instead of 24) — after 3 steps
// lane l holds the full dot for edge (l&4? B:A), row (l&3)*8 + (l>>3).
__global__ __launch_bounds__(256)
void transform_scatter_kernel(const float* __restrict__ theta,
                              const float* __restrict__ W,
                              const float* __restrict__ bia,
                              const int* __restrict__ src,
                              const int* __restrict__ tgt,
                              float* __restrict__ out) {
    const int lane = threadIdx.x & 63;
    const int wave = (blockIdx.x * blockDim.x + threadIdx.x) >> 6;

    const int j0    = (lane & 7) << 2;        // this lane's 4-wide col slice
    const int g     = lane >> 3;              // row-group within the 8-row band
    const int myRow = (lane & 3) * 8 + g;     // row this lane finally owns
    const int hiB   = (lane >> 2) & 1;        // 1 -> this lane owns edge B

    for (int it = 0; it < PAIRS_PER_WAVE; ++it) {
        const int p = wave + it * NWAVES;
        const int e = 2 * p;

        const int2 sp = *reinterpret_cast<const int2*>(src + e);  // {sA, sB}
        const int2 tp = *reinterpret_cast<const int2*>(tgt + e);  // {tA, tB}

        const f32x4 xA = *reinterpret_cast<const f32x4*>(theta + (size_t)sp.x * DSZ + j0);
        const f32x4 xB = *reinterpret_cast<const f32x4*>(theta + (size_t)sp.y * DSZ + j0);

        const f32x4* WA = reinterpret_cast<const f32x4*>(W + (size_t)e * (DSZ * DSZ));
        const f32x4* WB = WA + 256;

        // 8 KiB in flight — nontemporal: W has zero reuse
        const f32x4 a0 = __builtin_nontemporal_load(WA +   0 + lane);
        const f32x4 a1 = __builtin_nontemporal_load(WA +  64 + lane);
        const f32x4 a2 = __builtin_nontemporal_load(WA + 128 + lane);
        const f32x4 a3 = __builtin_nontemporal_load(WA + 192 + lane);
        const f32x4 c0 = __builtin_nontemporal_load(WB +   0 + lane);
        const f32x4 c1 = __builtin_nontemporal_load(WB +  64 + lane);
        const f32x4 c2 = __builtin_nontemporal_load(WB + 128 + lane);
        const f32x4 c3 = __builtin_nontemporal_load(WB + 192 + lane);

        // one bias element per lane (its own edge + row)
        const float biasv =
            __builtin_nontemporal_load(bia + ((size_t)e + hiB) * DSZ + myRow);

        float pA0 = a0.x * xA.x + a0.y * xA.y + a0.z * xA.z + a0.w * xA.w;
        float pA1 = a1.x * xA.x + a1.y * xA.y + a1.z * xA.z + a1.w * xA.w;
        float pA2 = a2.x * xA.x + a2.y * xA.y + a2.z * xA.z + a2.w * xA.w;
        float pA3 = a3.x * xA.x + a3.y * xA.y + a3.z * xA.z + a3.w * xA.w;
        float pB0 = c0.x * xB.x + c0.y * xB.y + c0.z * xB.z + c0.w * xB.w;
        float pB1 = c1.x * xB.x + c1.y * xB.y + c1.z * xB.z + c1.w * xB.w;
        float pB2 = c2.x * xB.x + c2.y * xB.y + c2.z * xB.z + c2.w * xB.w;
        float pB3 = c3.x * xB.x + c3.y * xB.y + c3.z * xB.z + c3.w * xB.w;

        // ---- value-splitting butterfly: 8 values over 8 lanes, 7 shfl ----
        const bool b0 = (lane & 1) != 0;
        const bool b1 = (lane & 2) != 0;
        const bool b2 = (lane & 4) != 0;

        // step 1 (xor 1): it-parity split
        float vA01 = b0 ? pA1 : pA0, oA01 = b0 ? pA0 : pA1;
        float vA23 = b0 ? pA3 : pA2, oA23 = b0 ? pA2 : pA3;
        float vB01 = b0 ? pB1 : pB0, oB01 = b0 ? pB0 : pB1;
        float vB23 = b0 ? pB3 : pB2, oB23 = b0 ? pB2 : pB3;
        vA01 += __shfl_xor(oA01, 1);
        vA23 += __shfl_xor(oA23, 1);
        vB01 += __shfl_xor(oB01, 1);
        vB23 += __shfl_xor(oB23, 1);

        // step 2 (xor 2): it-high-bit split; lane now holds it = l&3
        float vA = b1 ? vA23 : vA01, oA = b1 ? vA01 : vA23;
        float vB = b1 ? vB23 : vB01, oB = b1 ? vB01 : vB23;
        vA += __shfl_xor(oA, 2);
        vB += __shfl_xor(oB, 2);

        // step 3 (xor 4): edge split; lane holds its final total
        float v = b2 ? vB : vA, o = b2 ? vA : vB;
        v += __shfl_xor(o, 4);

        const int te = b2 ? tp.y : tp.x;
        atomicAdd(out + (size_t)te * DSZ + myRow, -(v + biasv));
    }
}

extern "C" void kernel_launch(void* const* d_in, const int* in_sizes, int n_in,
                              void* d_out, int out_size, void* d_ws, size_t ws_size,
                              hipStream_t stream) {
    const float* theta = (const float*)d_in[0];
    const float* W     = (const float*)d_in[1];
    const float* b     = (const float*)d_in[2];
    const int*   src   = (const int*)d_in[3];
    const int*   tgt   = (const int*)d_in[4];
    float* out = (float*)d_out;

    // 1) out = theta (single pass)
    const int n4 = (N_VARS * DSZ) / 4;             // 400,000 float4s
    copy_theta_kernel<<<(n4 + 255) / 256, 256, 0, stream>>>(
        (const float4*)theta, (float4*)out, n4);

    // 2) scatter transforms: 4000 waves, pair grid-stride (global sliding window)
    transform_scatter_kernel<<<NWAVES / 4, 256, 0, stream>>>(theta, W, b, src, tgt, out);
}